// Round 12
// baseline (225.801 us; speedup 1.0000x reference)
//
#include <hip/hip_runtime.h>
#include <hip/hip_bf16.h>

typedef __attribute__((ext_vector_type(8))) short s16x8;
typedef __attribute__((ext_vector_type(4))) float f32x4;
typedef _Float16 h16x8 __attribute__((ext_vector_type(8)));
typedef __fp16 fp16x2 __attribute__((ext_vector_type(2)));

// Merged prep: emb f32->f16 (n8 groups of 8) + W1 [K][N] -> W1T [N][K] f16.
__global__ void prep_all(const float* __restrict__ emb, _Float16* __restrict__ emb16,
                         const float* __restrict__ W1, short* __restrict__ W1T,
                         int n8) {
    int u = blockIdx.x * 256 + threadIdx.x;
    if (u < n8) {
        const float4 a = ((const float4*)emb)[u * 2];
        const float4 b = ((const float4*)emb)[u * 2 + 1];
        h16x8 h;
        h[0] = (_Float16)a.x; h[1] = (_Float16)a.y;
        h[2] = (_Float16)a.z; h[3] = (_Float16)a.w;
        h[4] = (_Float16)b.x; h[5] = (_Float16)b.y;
        h[6] = (_Float16)b.z; h[7] = (_Float16)b.w;
        *(h16x8*)(emb16 + u * 8) = h;
    } else {
        int v = u - n8;                 // 0..8191: 8 W1T elems each
        if (v < 8192) {
            int n = v >> 5, k0 = (v & 31) * 8;
            h16x8 h;
#pragma unroll
            for (int j = 0; j < 8; ++j)
                h[j] = (_Float16)W1[(k0 + j) * 256 + n];
            *(h16x8*)((_Float16*)W1T + n * 256 + k0) = h;
        }
    }
}

#define NBLK 256
#define BM 256

// Persistent: 256 blocks x 1024 threads (16 waves = 4 row-groups x 4 col-
// groups; 4 waves/SIMD). Block tile 256x256, wave tile 64x64 (acc[4][4]):
// 8 LDS reads per 16 MFMAs (0.5/MFMA, was 0.75). K in 8 slices of 32,
// double-buffered (2 x 16 KB); Blds 128 KB; total LDS = 160 KiB exactly.
// 4 rotating gather windows, 3-barrier load-to-use distance, cross-tile
// prefetch at s=5..7. b1 folded into acc init. Red aliases Abuf[1].
__global__ __launch_bounds__(1024)
void pair_mlp_f16(const int* __restrict__ pidx, const int* __restrict__ qidx,
                  const _Float16* __restrict__ emb, const short* __restrict__ w1t,
                  const float* __restrict__ b1, const float* __restrict__ w2,
                  const float* __restrict__ b2p, float* __restrict__ out,
                  int M, int NT)
{
    __shared__ short Blds[256 * 256];     // 128 KB: [col][kgran ^ (col&7)]
    __shared__ short Abuf[2][BM * 32];    // 2 x 16 KB K=32 slices (f16 bits)
    float* Red = (float*)&Abuf[1][0];     // 4 KB, aliased (dead at epilogue)

    const int tid  = threadIdx.x;
    const int lane = tid & 63;
    const int wv   = tid >> 6;     // 0..15
    const int c    = lane & 15;
    const int g    = lane >> 4;
    const int rg   = wv >> 2;      // row-group (64 rows)
    const int cg   = wv & 3;       // col-group (64 cols)

    // ---- stage W1T -> LDS once ----
#pragma unroll
    for (int it = 0; it < 8; ++it) {
        int G = it * 1024 + tid;
        int col = G >> 5, kg = G & 31;
        s16x8 v = *(const s16x8*)(w1t + G * 8);
        *(s16x8*)(Blds + (col * 32 + (kg ^ (col & 7))) * 8) = v;
    }
    const float b2v = b2p[0];

    // A-read addresses (f16 units), slice-invariant: row R = rg*64+m*16+c,
    // slot = g ^ ((R>>1)&3) = g ^ ((c>>1)&3)
    int araddr[4];
#pragma unroll
    for (int m = 0; m < 4; ++m) {
        int R = rg * 64 + m * 16 + c;
        araddr[m] = R * 32 + ((g ^ ((c >> 1) & 3)) * 8);
    }
    int bcol[4];
#pragma unroll
    for (int n = 0; n < 4; ++n) bcol[n] = (cg * 64 + n * 16 + c) * 256;
    const int bx = c & 7;

    // conv role: 4 threads per row (sg = 8-f16 segment of the K=32 slice)
    const int r  = tid >> 2;       // 0..255
    const int sg = tid & 3;
    const int wbase = r * 32 + ((sg ^ ((r >> 1) & 3)) * 8);

    __syncthreads();

    int im0 = blockIdx.x * BM + r; im0 = im0 < M ? im0 : M - 1;
    int pi = pidx[im0], qi = qidx[im0];

    h16x8 wp[4], wq[4];            // 4 rotating windows (8 f16 each side)

#define LD(W, PP, QP, S)                                                 \
    {                                                                    \
        wp[W] = *(const h16x8*)((PP) + (S) * 32);                        \
        wq[W] = *(const h16x8*)((QP) + (S) * 32);                        \
    }

#define CONV(W, BUF)                                                     \
    {                                                                    \
        h16x8 d = wp[W] - wq[W];                                         \
        h16x8 sq = d * d;                                                \
        *(h16x8*)(&Abuf[BUF][0] + wbase) = sq;                           \
    }

#define MFMA_SLICE(S, BUFI)                                              \
    {                                                                    \
        const short* ab = &Abuf[BUFI][0];                                \
        h16x8 af0 = *(const h16x8*)(ab + araddr[0]);                     \
        h16x8 af1 = *(const h16x8*)(ab + araddr[1]);                     \
        h16x8 af2 = *(const h16x8*)(ab + araddr[2]);                     \
        h16x8 af3 = *(const h16x8*)(ab + araddr[3]);                     \
        __builtin_amdgcn_s_setprio(1);                                   \
        _Pragma("unroll")                                                \
        for (int n = 0; n < 4; ++n) {                                    \
            h16x8 bf = *(const h16x8*)(Blds + bcol[n] +                  \
                                       ((((S) * 4 + g) ^ bx) * 8));      \
            acc[0][n] = __builtin_amdgcn_mfma_f32_16x16x32_f16(bf, af0, acc[0][n], 0, 0, 0); \
            acc[1][n] = __builtin_amdgcn_mfma_f32_16x16x32_f16(bf, af1, acc[1][n], 0, 0, 0); \
            acc[2][n] = __builtin_amdgcn_mfma_f32_16x16x32_f16(bf, af2, acc[2][n], 0, 0, 0); \
            acc[3][n] = __builtin_amdgcn_mfma_f32_16x16x32_f16(bf, af3, acc[3][n], 0, 0, 0); \
        }                                                                \
        __builtin_amdgcn_s_setprio(0);                                   \
    }

    // ---- first-tile prologue: windows w0..w2 = slices 0..2; conv slice 0 ----
    {
        const _Float16* pp = emb + (size_t)pi * 256 + sg * 8;
        const _Float16* qp = emb + (size_t)qi * 256 + sg * 8;
        LD(0, pp, qp, 0)
        LD(1, pp, qp, 1)
        LD(2, pp, qp, 2)
        CONV(0, 0)
    }

    for (int tile = blockIdx.x; tile < NT; tile += NBLK) {
        const int base = tile * BM;
        const _Float16* pp = emb + (size_t)pi * 256 + sg * 8;
        const _Float16* qp = emb + (size_t)qi * 256 + sg * 8;

        // prefetch next tile's indices
        int pi_n = pi, qi_n = qi;
        {
            int t2 = tile + NBLK;
            if (t2 < NT) {
                int im2 = t2 * BM + r; im2 = im2 < M ? im2 : M - 1;
                pi_n = pidx[im2]; qi_n = qidx[im2];
            }
        }
        const _Float16* pp_n = emb + (size_t)pi_n * 256 + sg * 8;
        const _Float16* qp_n = emb + (size_t)qi_n * 256 + sg * 8;

        // acc init = b1 (folded bias; b1q dead after init)
        f32x4 acc[4][4];
        {
            f32x4 b1q[4];
#pragma unroll
            for (int n = 0; n < 4; ++n)
                b1q[n] = *(const f32x4*)(b1 + cg * 64 + n * 16 + g * 4);
#pragma unroll
            for (int m = 0; m < 4; ++m)
#pragma unroll
                for (int n = 0; n < 4; ++n) acc[m][n] = b1q[n];
        }

        // s=0..7: bar; LD(w[s&3] <- slice s+3 / next-tile); MFMA(s); CONV(w[(s+1)&3])
        __syncthreads(); LD(3, pp, qp, 3)    MFMA_SLICE(0, 0) CONV(1, 1)
        __syncthreads(); LD(0, pp, qp, 4)    MFMA_SLICE(1, 1) CONV(2, 0)
        __syncthreads(); LD(1, pp, qp, 5)    MFMA_SLICE(2, 0) CONV(3, 1)
        __syncthreads(); LD(2, pp, qp, 6)    MFMA_SLICE(3, 1) CONV(0, 0)
        __syncthreads(); LD(3, pp, qp, 7)    MFMA_SLICE(4, 0) CONV(1, 1)
        __syncthreads(); LD(0, pp_n, qp_n, 0) MFMA_SLICE(5, 1) CONV(2, 0)
        __syncthreads(); LD(1, pp_n, qp_n, 1) MFMA_SLICE(6, 0) CONV(3, 1)
        __syncthreads(); LD(2, pp_n, qp_n, 2) MFMA_SLICE(7, 1) CONV(0, 0)
        // w0 conv'd next tile's slice 0 into buf0; w1/w2 hold next slices 1/2

        // ---- epilogue: h includes b1; relu-dot with w2, reduce over g ----
        float part[4];
        {
            f32x4 w2q[4];
#pragma unroll
            for (int n = 0; n < 4; ++n)
                w2q[n] = *(const f32x4*)(w2 + cg * 64 + n * 16 + g * 4);
#pragma unroll
            for (int m = 0; m < 4; ++m) {
                float s = 0.f;
#pragma unroll
                for (int n = 0; n < 4; ++n)
#pragma unroll
                    for (int j = 0; j < 4; ++j) {
                        float h = acc[m][n][j];
                        h = h > 0.f ? h : 0.f;
                        s += h * w2q[n][j];
                    }
                part[m] = s;
            }
        }
#pragma unroll
        for (int m = 0; m < 4; ++m) {
            part[m] += __shfl_xor(part[m], 16, 64);
            part[m] += __shfl_xor(part[m], 32, 64);
        }

        __syncthreads();            // all buf1 MFMA reads done (Red aliases it)
        if (g == 0) {
#pragma unroll
            for (int m = 0; m < 4; ++m)
                Red[cg * BM + rg * 64 + m * 16 + c] = part[m];
        }
        __syncthreads();
        if (tid < BM) {
            int row = base + tid;
            if (row < M)
                out[row] = b2v + Red[tid] + Red[BM + tid] +
                           Red[2 * BM + tid] + Red[3 * BM + tid];
        }
        pi = pi_n; qi = qi_n;
        // next tile: s=0 barrier orders Red reads before CONV(1 -> buf1)
    }
#undef LD
#undef CONV
#undef MFMA_SLICE
}

// ---------------- f32-gather fallback (only if ws too small for emb16) ----
__global__ void prep_w1t_only(const float* __restrict__ W1, short* __restrict__ W1T) {
    int t = blockIdx.x * 256 + threadIdx.x;
    int n = t >> 8, k = t & 255;
    union { _Float16 h; short s; } u;
    u.h = (_Float16)W1[k * 256 + n];
    W1T[t] = u.s;
}

__global__ __launch_bounds__(1024)
void pair_mlp_f32(const int* __restrict__ pidx, const int* __restrict__ qidx,
                  const float* __restrict__ emb, const short* __restrict__ w1t,
                  const float* __restrict__ b1, const float* __restrict__ w2,
                  const float* __restrict__ b2p, float* __restrict__ out,
                  int M, int NT)
{
    __shared__ short Blds[256 * 256];
    __shared__ short Abuf[2][128 * 64];
    float* Red = (float*)&Abuf[1][0];

    const int tid  = threadIdx.x;
    const int lane = tid & 63;
    const int wv   = tid >> 6;
    const int c    = lane & 15;
    const int g    = lane >> 4;
    const int cg   = wv & 7;
    const int rh   = wv >> 3;

#pragma unroll
    for (int it = 0; it < 8; ++it) {
        int G = it * 1024 + tid;
        int col = G >> 5, kg = G & 31;
        s16x8 v = *(const s16x8*)(w1t + G * 8);
        *(s16x8*)(Blds + (col * 32 + (kg ^ (col & 7))) * 8) = v;
    }

    f32x4 b1q[2];
    float w2v[2][4];
#pragma unroll
    for (int n = 0; n < 2; ++n)
#pragma unroll
        for (int j = 0; j < 4; ++j) {
            b1q[n][j] = b1[cg * 32 + n * 16 + g * 4 + j];
            w2v[n][j] = w2[cg * 32 + n * 16 + g * 4 + j];
        }
    const float b2v = b2p[0];
    __syncthreads();

    const int r  = tid >> 3;
    const int sg = tid & 7;
    const int wslot = (sg ^ (r & 7)) * 8;

    int im0 = blockIdx.x * 128 + r; im0 = im0 < M ? im0 : M - 1;
    int pi = pidx[im0], qi = qidx[im0];

#define LOADW(W, S)                                                      \
    {                                                                    \
        const float* ps = pp + (S) * 64;                                 \
        const float* qs = qp + (S) * 64;                                 \
        P0_##W = ((const float4*)ps)[0]; P1_##W = ((const float4*)ps)[1];\
        Q0_##W = ((const float4*)qs)[0]; Q1_##W = ((const float4*)qs)[1];\
    }

#define CONVF(W, BUF)                                                    \
    {                                                                    \
        float d0 = P0_##W.x - Q0_##W.x, d1 = P0_##W.y - Q0_##W.y;        \
        float d2 = P0_##W.z - Q0_##W.z, d3 = P0_##W.w - Q0_##W.w;        \
        float d4 = P1_##W.x - Q1_##W.x, d5 = P1_##W.y - Q1_##W.y;        \
        float d6 = P1_##W.z - Q1_##W.z, d7 = P1_##W.w - Q1_##W.w;        \
        union { h16x8 v; fp16x2 p[4]; } a;                               \
        a.p[0] = __builtin_amdgcn_cvt_pkrtz(d0 * d0, d1 * d1);           \
        a.p[1] = __builtin_amdgcn_cvt_pkrtz(d2 * d2, d3 * d3);           \
        a.p[2] = __builtin_amdgcn_cvt_pkrtz(d4 * d4, d5 * d5);           \
        a.p[3] = __builtin_amdgcn_cvt_pkrtz(d6 * d6, d7 * d7);           \
        *(h16x8*)(&Abuf[BUF][0] + r * 64 + wslot) = a.v;                 \
    }

#define MFMA_STEPF(S, BUF)                                               \
    {                                                                    \
        const short* ab = &Abuf[BUF][0];                                 \
        _Pragma("unroll")                                                \
        for (int kk = 0; kk < 2; ++kk) {                                 \
            int bs = ((S) * 8 + kk * 4 + g) ^ (c & 7);                   \
            h16x8 bf0 = *(const h16x8*)(Blds + ((cg * 32 + c) * 32 + bs) * 8);      \
            h16x8 bf1 = *(const h16x8*)(Blds + ((cg * 32 + 16 + c) * 32 + bs) * 8); \
            _Pragma("unroll")                                            \
            for (int m = 0; m < 4; ++m) {                                \
                int row = rh * 64 + m * 16 + c;                          \
                h16x8 af = *(const h16x8*)(ab + row * 64 +               \
                                           (((kk * 4 + g) ^ (c & 7)) * 8)); \
                acc[m][0] = __builtin_amdgcn_mfma_f32_16x16x32_f16(      \
                    bf0, af, acc[m][0], 0, 0, 0);                        \
                acc[m][1] = __builtin_amdgcn_mfma_f32_16x16x32_f16(      \
                    bf1, af, acc[m][1], 0, 0, 0);                        \
            }                                                            \
        }                                                                \
    }

    for (int tile = blockIdx.x; tile < NT; tile += NBLK) {
        const int base = tile * 128;
        const float* pp = emb + (size_t)pi * 256 + sg * 8;
        const float* qp = emb + (size_t)qi * 256 + sg * 8;

        float4 P0_0, P1_0, Q0_0, Q1_0, P0_1, P1_1, Q0_1, Q1_1;
        LOADW(0, 0)
        LOADW(1, 1)

        int pi_n = pi, qi_n = qi;
        {
            int t2 = tile + NBLK;
            if (t2 < NT) {
                int im2 = t2 * 128 + r; im2 = im2 < M ? im2 : M - 1;
                pi_n = pidx[im2]; qi_n = qidx[im2];
            }
        }

        CONVF(0, 0)

        f32x4 acc[4][2];
#pragma unroll
        for (int m = 0; m < 4; ++m) { acc[m][0] = b1q[0]; acc[m][1] = b1q[1]; }

        __syncthreads();
        LOADW(0, 2)
        MFMA_STEPF(0, 0)
        CONVF(1, 1)
        __syncthreads();
        LOADW(1, 3)
        MFMA_STEPF(1, 1)
        CONVF(0, 0)
        __syncthreads();
        MFMA_STEPF(2, 0)
        CONVF(1, 1)
        __syncthreads();
        MFMA_STEPF(3, 1)

        float part[4];
#pragma unroll
        for (int m = 0; m < 4; ++m) {
            float s = 0.f;
#pragma unroll
            for (int n = 0; n < 2; ++n)
#pragma unroll
                for (int j = 0; j < 4; ++j) {
                    float h = acc[m][n][j];
                    h = h > 0.f ? h : 0.f;
                    s += h * w2v[n][j];
                }
            part[m] = s;
        }
#pragma unroll
        for (int m = 0; m < 4; ++m) {
            part[m] += __shfl_xor(part[m], 16, 64);
            part[m] += __shfl_xor(part[m], 32, 64);
        }

        __syncthreads();
        if (g == 0) {
#pragma unroll
            for (int m = 0; m < 4; ++m)
                Red[cg * 128 + rh * 64 + m * 16 + c] = part[m];
        }
        __syncthreads();
        if (tid < 128) {
            int row = base + tid;
            if (row < M) {
                float s = b2v;
#pragma unroll
                for (int k = 0; k < 8; ++k) s += Red[k * 128 + tid];
                out[row] = s;
            }
        }
        pi = pi_n; qi = qi_n;
    }
#undef LOADW
#undef CONVF
#undef MFMA_STEPF
}

extern "C" void kernel_launch(void* const* d_in, const int* in_sizes, int n_in,
                              void* d_out, int out_size, void* d_ws, size_t ws_size,
                              hipStream_t stream) {
    const int*   p   = (const int*)d_in[0];
    const int*   q   = (const int*)d_in[1];
    const float* emb = (const float*)d_in[2];
    const float* W1  = (const float*)d_in[3];
    const float* b1  = (const float*)d_in[4];
    const float* W2  = (const float*)d_in[5];
    const float* b2  = (const float*)d_in[6];
    float* out = (float*)d_out;
    int M = in_sizes[0];
    int embElems = in_sizes[2];            // 100000 * 256
    int NT = (M + BM - 1) / BM;

    short* w1t = (short*)d_ws;             // 128 KB at offset 0
    size_t embOff = 131072;
    size_t need = embOff + (size_t)embElems * 2;

    if (ws_size >= need) {
        _Float16* emb16 = (_Float16*)((char*)d_ws + embOff);
        int n8 = embElems / 8;             // 3,200,000
        int total = n8 + 8192;
        prep_all<<<(total + 255) / 256, 256, 0, stream>>>(emb, emb16, W1, w1t, n8);
        pair_mlp_f16<<<NBLK, 1024, 0, stream>>>(p, q, emb16, w1t, b1, W2, b2,
                                                out, M, NT);
    } else {
        int NT128 = (M + 127) / 128;
        prep_w1t_only<<<256, 256, 0, stream>>>(W1, w1t);
        pair_mlp_f32<<<NBLK, 1024, 0, stream>>>(p, q, emb, w1t, b1, W2, b2,
                                                out, M, NT128);
    }
}

// Round 13
// 104.310 us; speedup vs baseline: 2.1647x; 2.1647x over previous
//
#include <hip/hip_runtime.h>
#include <hip/hip_bf16.h>

typedef __attribute__((ext_vector_type(8))) short s16x8;
typedef __attribute__((ext_vector_type(4))) float f32x4;
typedef _Float16 h16x8 __attribute__((ext_vector_type(8)));
typedef __fp16 fp16x2 __attribute__((ext_vector_type(2)));

// Merged prep: emb f32->f16 (n8 groups of 8) + W1 [K][N] -> W1T [N][K] f16.
__global__ void prep_all(const float* __restrict__ emb, _Float16* __restrict__ emb16,
                         const float* __restrict__ W1, short* __restrict__ W1T,
                         int n8) {
    int u = blockIdx.x * 256 + threadIdx.x;
    if (u < n8) {
        const float4 a = ((const float4*)emb)[u * 2];
        const float4 b = ((const float4*)emb)[u * 2 + 1];
        h16x8 h;
        h[0] = (_Float16)a.x; h[1] = (_Float16)a.y;
        h[2] = (_Float16)a.z; h[3] = (_Float16)a.w;
        h[4] = (_Float16)b.x; h[5] = (_Float16)b.y;
        h[6] = (_Float16)b.z; h[7] = (_Float16)b.w;
        *(h16x8*)(emb16 + u * 8) = h;
    } else {
        int v = u - n8;                 // 0..8191: 8 W1T elems each
        if (v < 8192) {
            int n = v >> 5, k0 = (v & 31) * 8;
            h16x8 h;
#pragma unroll
            for (int j = 0; j < 8; ++j)
                h[j] = (_Float16)W1[(k0 + j) * 256 + n];
            *(h16x8*)((_Float16*)W1T + n * 256 + k0) = h;
        }
    }
}

#define NBLK 256

// Best measured config (r11: main 85-90 us, total 104 us): persistent
// 256 blocks x 1024 threads (16 waves, 4/SIMD). LDS: full W1T f16 (128 KB,
// XOR-swizzled) + double-buffered A K=64 slices (2 x 16 KB) = 160 KiB;
// Red aliases Abuf[1]. Packed-f16 conv; f16 MFMA; b1 folded into acc init;
// 4 rotating cross-tile gather windows. Gather-BW-bound at ~5.7 TB/s.
__global__ __launch_bounds__(1024)
void pair_mlp_f16(const int* __restrict__ pidx, const int* __restrict__ qidx,
                  const _Float16* __restrict__ emb, const short* __restrict__ w1t,
                  const float* __restrict__ b1, const float* __restrict__ w2,
                  const float* __restrict__ b2p, float* __restrict__ out,
                  int M, int NT)
{
    __shared__ short Blds[256 * 256];     // 128 KB: [col][kgran ^ (col&7)]
    __shared__ short Abuf[2][128 * 64];   // 2 x 16 KB K-slices (f16 bits)
    float* Red = (float*)&Abuf[1][0];     // 4 KB, aliased (dead at epilogue)

    const int tid  = threadIdx.x;
    const int lane = tid & 63;
    const int wv   = tid >> 6;     // 0..15
    const int c    = lane & 15;
    const int g    = lane >> 4;
    const int cg   = wv & 7;       // col-group (32 cols)
    const int rh   = wv >> 3;      // row-half (64 rows)

    // ---- stage W1T -> LDS once ----
#pragma unroll
    for (int it = 0; it < 8; ++it) {
        int G = it * 1024 + tid;
        int col = G >> 5, kg = G & 31;
        s16x8 v = *(const s16x8*)(w1t + G * 8);
        *(s16x8*)(Blds + (col * 32 + (kg ^ (col & 7))) * 8) = v;
    }

    // epilogue constants: cols cg*32 + n*16 + g*4 + j
    f32x4 b1q[2];
    float w2v[2][4];
#pragma unroll
    for (int n = 0; n < 2; ++n)
#pragma unroll
        for (int j = 0; j < 4; ++j) {
            b1q[n][j]  = b1[cg * 32 + n * 16 + g * 4 + j];
            w2v[n][j]  = w2[cg * 32 + n * 16 + g * 4 + j];
        }
    const float b2v = b2p[0];
    __syncthreads();

    const int r  = tid >> 3;       // gather row 0..127
    const int sg = tid & 7;        // 8-elem K-granule within 64-K slice
    const int wslot = (sg ^ (r & 7)) * 8;

    int im0 = blockIdx.x * 128 + r; im0 = im0 < M ? im0 : M - 1;
    int pi = pidx[im0], qi = qidx[im0];

    h16x8 wp[4], wq[4];            // 4 rotating windows

#define LD(W, PP, QP, S)                                                 \
    {                                                                    \
        wp[W] = *(const h16x8*)((PP) + (S) * 64);                        \
        wq[W] = *(const h16x8*)((QP) + (S) * 64);                        \
    }

// packed f16: d = p - q; s = d*d  (v_pk_sub_f16 x4, v_pk_mul_f16 x4)
#define CONV(W, BUF)                                                     \
    {                                                                    \
        h16x8 d = wp[W] - wq[W];                                         \
        h16x8 s = d * d;                                                 \
        *(h16x8*)(&Abuf[BUF][0] + r * 64 + wslot) = s;                   \
    }

#define MFMA_STEP(S, BUF)                                                \
    {                                                                    \
        const short* ab = &Abuf[BUF][0];                                 \
        __builtin_amdgcn_s_setprio(1);                                   \
        _Pragma("unroll")                                                \
        for (int kk = 0; kk < 2; ++kk) {                                 \
            int bs = ((S) * 8 + kk * 4 + g) ^ (c & 7);                   \
            h16x8 bf0 = *(const h16x8*)(Blds + ((cg * 32 + c) * 32 + bs) * 8);      \
            h16x8 bf1 = *(const h16x8*)(Blds + ((cg * 32 + 16 + c) * 32 + bs) * 8); \
            _Pragma("unroll")                                            \
            for (int m = 0; m < 4; ++m) {                                \
                int row = rh * 64 + m * 16 + c;                          \
                h16x8 af = *(const h16x8*)(ab + row * 64 +               \
                                           (((kk * 4 + g) ^ (c & 7)) * 8)); \
                acc[m][0] = __builtin_amdgcn_mfma_f32_16x16x32_f16(      \
                    bf0, af, acc[m][0], 0, 0, 0);                        \
                acc[m][1] = __builtin_amdgcn_mfma_f32_16x16x32_f16(      \
                    bf1, af, acc[m][1], 0, 0, 0);                        \
            }                                                            \
        }                                                                \
        __builtin_amdgcn_s_setprio(0);                                   \
    }

    // ---- first-tile prologue: windows w0..w2 ----
    {
        const _Float16* pp = emb + (size_t)pi * 256 + sg * 8;
        const _Float16* qp = emb + (size_t)qi * 256 + sg * 8;
        LD(0, pp, qp, 0)
        LD(1, pp, qp, 1)
        LD(2, pp, qp, 2)
    }

    for (int tile = blockIdx.x; tile < NT; tile += NBLK) {
        const int base = tile * 128;
        const _Float16* pp = emb + (size_t)pi * 256 + sg * 8;
        const _Float16* qp = emb + (size_t)qi * 256 + sg * 8;

        // prefetch next tile's indices
        int pi_n = pi, qi_n = qi;
        {
            int t2 = tile + NBLK;
            if (t2 < NT) {
                int im2 = t2 * 128 + r; im2 = im2 < M ? im2 : M - 1;
                pi_n = pidx[im2]; qi_n = qidx[im2];
            }
        }

        CONV(0, 0)

        f32x4 acc[4][2];
#pragma unroll
        for (int m = 0; m < 4; ++m) { acc[m][0] = b1q[0]; acc[m][1] = b1q[1]; }

        // s = 0
        __syncthreads();
        LD(3, pp, qp, 3)
        MFMA_STEP(0, 0)
        CONV(1, 1)

        const _Float16* pp_n = emb + (size_t)pi_n * 256 + sg * 8;
        const _Float16* qp_n = emb + (size_t)qi_n * 256 + sg * 8;

        // s = 1
        __syncthreads();
        LD(0, pp_n, qp_n, 0)
        MFMA_STEP(1, 1)
        CONV(2, 0)
        // s = 2
        __syncthreads();
        LD(1, pp_n, qp_n, 1)
        MFMA_STEP(2, 0)
        CONV(3, 1)
        // s = 3
        __syncthreads();
        LD(2, pp_n, qp_n, 2)
        MFMA_STEP(3, 1)

        // ---- epilogue: h already includes b1; relu-dot, reduce over g ----
        float part[4];
#pragma unroll
        for (int m = 0; m < 4; ++m) {
            float s = 0.f;
#pragma unroll
            for (int n = 0; n < 2; ++n)
#pragma unroll
                for (int j = 0; j < 4; ++j) {
                    float h = acc[m][n][j];
                    h = h > 0.f ? h : 0.f;
                    s += h * w2v[n][j];
                }
            part[m] = s;
        }
#pragma unroll
        for (int m = 0; m < 4; ++m) {
            part[m] += __shfl_xor(part[m], 16, 64);
            part[m] += __shfl_xor(part[m], 32, 64);
        }

        __syncthreads();            // buf1 MFMA reads done (Red aliases it)
        if (g == 0) {
#pragma unroll
            for (int m = 0; m < 4; ++m)
                Red[cg * 128 + rh * 64 + m * 16 + c] = part[m];
        }
        __syncthreads();
        if (tid < 128) {
            int row = base + tid;
            if (row < M) {
                float s = b2v;
#pragma unroll
                for (int k = 0; k < 8; ++k) s += Red[k * 128 + tid];
                out[row] = s;
            }
        }
        pi = pi_n; qi = qi_n;
    }
#undef LD
#undef CONV
#undef MFMA_STEP
}

// ---------------- f32-gather fallback (only if ws too small for emb16) ----
__global__ void prep_w1t_only(const float* __restrict__ W1, short* __restrict__ W1T) {
    int t = blockIdx.x * 256 + threadIdx.x;
    int n = t >> 8, k = t & 255;
    union { _Float16 h; short s; } u;
    u.h = (_Float16)W1[k * 256 + n];
    W1T[t] = u.s;
}

__global__ __launch_bounds__(1024)
void pair_mlp_f32(const int* __restrict__ pidx, const int* __restrict__ qidx,
                  const float* __restrict__ emb, const short* __restrict__ w1t,
                  const float* __restrict__ b1, const float* __restrict__ w2,
                  const float* __restrict__ b2p, float* __restrict__ out,
                  int M, int NT)
{
    __shared__ short Blds[256 * 256];
    __shared__ short Abuf[2][128 * 64];
    float* Red = (float*)&Abuf[1][0];

    const int tid  = threadIdx.x;
    const int lane = tid & 63;
    const int wv   = tid >> 6;
    const int c    = lane & 15;
    const int g    = lane >> 4;
    const int cg   = wv & 7;
    const int rh   = wv >> 3;

#pragma unroll
    for (int it = 0; it < 8; ++it) {
        int G = it * 1024 + tid;
        int col = G >> 5, kg = G & 31;
        s16x8 v = *(const s16x8*)(w1t + G * 8);
        *(s16x8*)(Blds + (col * 32 + (kg ^ (col & 7))) * 8) = v;
    }

    f32x4 b1q[2];
    float w2v[2][4];
#pragma unroll
    for (int n = 0; n < 2; ++n)
#pragma unroll
        for (int j = 0; j < 4; ++j) {
            b1q[n][j] = b1[cg * 32 + n * 16 + g * 4 + j];
            w2v[n][j] = w2[cg * 32 + n * 16 + g * 4 + j];
        }
    const float b2v = b2p[0];
    __syncthreads();

    const int r  = tid >> 3;
    const int sg = tid & 7;
    const int wslot = (sg ^ (r & 7)) * 8;

    int im0 = blockIdx.x * 128 + r; im0 = im0 < M ? im0 : M - 1;
    int pi = pidx[im0], qi = qidx[im0];

#define LOADW(W, S)                                                      \
    {                                                                    \
        const float* ps = pp + (S) * 64;                                 \
        const float* qs = qp + (S) * 64;                                 \
        P0_##W = ((const float4*)ps)[0]; P1_##W = ((const float4*)ps)[1];\
        Q0_##W = ((const float4*)qs)[0]; Q1_##W = ((const float4*)qs)[1];\
    }

#define CONVF(W, BUF)                                                    \
    {                                                                    \
        float d0 = P0_##W.x - Q0_##W.x, d1 = P0_##W.y - Q0_##W.y;        \
        float d2 = P0_##W.z - Q0_##W.z, d3 = P0_##W.w - Q0_##W.w;        \
        float d4 = P1_##W.x - Q1_##W.x, d5 = P1_##W.y - Q1_##W.y;        \
        float d6 = P1_##W.z - Q1_##W.z, d7 = P1_##W.w - Q1_##W.w;        \
        union { h16x8 v; fp16x2 p[4]; } a;                               \
        a.p[0] = __builtin_amdgcn_cvt_pkrtz(d0 * d0, d1 * d1);           \
        a.p[1] = __builtin_amdgcn_cvt_pkrtz(d2 * d2, d3 * d3);           \
        a.p[2] = __builtin_amdgcn_cvt_pkrtz(d4 * d4, d5 * d5);           \
        a.p[3] = __builtin_amdgcn_cvt_pkrtz(d6 * d6, d7 * d7);           \
        *(h16x8*)(&Abuf[BUF][0] + r * 64 + wslot) = a.v;                 \
    }

#define MFMA_STEPF(S, BUF)                                               \
    {                                                                    \
        const short* ab = &Abuf[BUF][0];                                 \
        _Pragma("unroll")                                                \
        for (int kk = 0; kk < 2; ++kk) {                                 \
            int bs = ((S) * 8 + kk * 4 + g) ^ (c & 7);                   \
            h16x8 bf0 = *(const h16x8*)(Blds + ((cg * 32 + c) * 32 + bs) * 8);      \
            h16x8 bf1 = *(const h16x8*)(Blds + ((cg * 32 + 16 + c) * 32 + bs) * 8); \
            _Pragma("unroll")                                            \
            for (int m = 0; m < 4; ++m) {                                \
                int row = rh * 64 + m * 16 + c;                          \
                h16x8 af = *(const h16x8*)(ab + row * 64 +               \
                                           (((kk * 4 + g) ^ (c & 7)) * 8)); \
                acc[m][0] = __builtin_amdgcn_mfma_f32_16x16x32_f16(      \
                    bf0, af, acc[m][0], 0, 0, 0);                        \
                acc[m][1] = __builtin_amdgcn_mfma_f32_16x16x32_f16(      \
                    bf1, af, acc[m][1], 0, 0, 0);                        \
            }                                                            \
        }                                                                \
    }

    for (int tile = blockIdx.x; tile < NT; tile += NBLK) {
        const int base = tile * 128;
        const float* pp = emb + (size_t)pi * 256 + sg * 8;
        const float* qp = emb + (size_t)qi * 256 + sg * 8;

        float4 P0_0, P1_0, Q0_0, Q1_0, P0_1, P1_1, Q0_1, Q1_1;
        LOADW(0, 0)
        LOADW(1, 1)

        int pi_n = pi, qi_n = qi;
        {
            int t2 = tile + NBLK;
            if (t2 < NT) {
                int im2 = t2 * 128 + r; im2 = im2 < M ? im2 : M - 1;
                pi_n = pidx[im2]; qi_n = qidx[im2];
            }
        }

        CONVF(0, 0)

        f32x4 acc[4][2];
#pragma unroll
        for (int m = 0; m < 4; ++m) { acc[m][0] = b1q[0]; acc[m][1] = b1q[1]; }

        __syncthreads();
        LOADW(0, 2)
        MFMA_STEPF(0, 0)
        CONVF(1, 1)
        __syncthreads();
        LOADW(1, 3)
        MFMA_STEPF(1, 1)
        CONVF(0, 0)
        __syncthreads();
        MFMA_STEPF(2, 0)
        CONVF(1, 1)
        __syncthreads();
        MFMA_STEPF(3, 1)

        float part[4];
#pragma unroll
        for (int m = 0; m < 4; ++m) {
            float s = 0.f;
#pragma unroll
            for (int n = 0; n < 2; ++n)
#pragma unroll
                for (int j = 0; j < 4; ++j) {
                    float h = acc[m][n][j];
                    h = h > 0.f ? h : 0.f;
                    s += h * w2v[n][j];
                }
            part[m] = s;
        }
#pragma unroll
        for (int m = 0; m < 4; ++m) {
            part[m] += __shfl_xor(part[m], 16, 64);
            part[m] += __shfl_xor(part[m], 32, 64);
        }

        __syncthreads();
        if (g == 0) {
#pragma unroll
            for (int m = 0; m < 4; ++m)
                Red[cg * 128 + rh * 64 + m * 16 + c] = part[m];
        }
        __syncthreads();
        if (tid < 128) {
            int row = base + tid;
            if (row < M) {
                float s = b2v;
#pragma unroll
                for (int k = 0; k < 8; ++k) s += Red[k * 128 + tid];
                out[row] = s;
            }
        }
        pi = pi_n; qi = qi_n;
    }
#undef LOADW
#undef CONVF
#undef MFMA_STEPF
}

extern "C" void kernel_launch(void* const* d_in, const int* in_sizes, int n_in,
                              void* d_out, int out_size, void* d_ws, size_t ws_size,
                              hipStream_t stream) {
    const int*   p   = (const int*)d_in[0];
    const int*   q   = (const int*)d_in[1];
    const float* emb = (const float*)d_in[2];
    const float* W1  = (const float*)d_in[3];
    const float* b1  = (const float*)d_in[4];
    const float* W2  = (const float*)d_in[5];
    const float* b2  = (const float*)d_in[6];
    float* out = (float*)d_out;
    int M = in_sizes[0];
    int embElems = in_sizes[2];            // 100000 * 256
    int NT = (M + 127) / 128;

    short* w1t = (short*)d_ws;             // 128 KB at offset 0
    size_t embOff = 131072;
    size_t need = embOff + (size_t)embElems * 2;

    if (ws_size >= need) {
        _Float16* emb16 = (_Float16*)((char*)d_ws + embOff);
        int n8 = embElems / 8;             // 3,200,000
        int total = n8 + 8192;
        prep_all<<<(total + 255) / 256, 256, 0, stream>>>(emb, emb16, W1, w1t, n8);
        pair_mlp_f16<<<NBLK, 1024, 0, stream>>>(p, q, emb16, w1t, b1, W2, b2,
                                                out, M, NT);
    } else {
        prep_w1t_only<<<256, 256, 0, stream>>>(W1, w1t);
        pair_mlp_f32<<<NBLK, 1024, 0, stream>>>(p, q, emb, w1t, b1, W2, b2,
                                                out, M, NT);
    }
}